// Round 20
// baseline (186.754 us; speedup 1.0000x reference)
//
#include <hip/hip_runtime.h>
#include <hip/hip_bf16.h>

#define BATCH  2
#define SEQ    2048
#define DMODEL 1024
#define NHEAD  16
#define DHEAD  64
#define NTOK   (BATCH * SEQ)

using f32x4  = __attribute__((ext_vector_type(4))) float;
using f32x16 = __attribute__((ext_vector_type(16))) float;
using s16x4  = __attribute__((ext_vector_type(4))) short;
using s16x8  = __attribute__((ext_vector_type(8))) short;

__device__ __forceinline__ short f2bf(float f) {
  __hip_bfloat16 h = __float2bfloat16(f);
  return *(short*)&h;
}

__device__ __forceinline__ void gload_lds16(const short* g, short* l) {
  __builtin_amdgcn_global_load_lds(
      (const __attribute__((address_space(1))) void*)g,
      (__attribute__((address_space(3))) void*)l, 16, 0, 0);
}

// ---------------------------------------------------------------------------
// prep: fused wtrans (blocks 0..1023) | xcast (1024..7167) | mpack (7168..8191)
// ---------------------------------------------------------------------------
__global__ __launch_bounds__(256) void prep_kernel(
    const float* __restrict__ Wq, const float* __restrict__ Wk,
    const float* __restrict__ Wv, const float* __restrict__ Wo,
    short* __restrict__ Wt,
    const float* __restrict__ Xq, const float* __restrict__ Xk,
    const float* __restrict__ Xv, short* __restrict__ Xb,
    const int* __restrict__ mask, unsigned long long* __restrict__ Mp) {
  __shared__ short tile[64][72];
  int bid = blockIdx.x, t = threadIdx.x;
  if (bid < 1024) {
    int z = bid >> 8, rem = bid & 255, x = rem & 15, y = rem >> 4;
    const float* W = z == 0 ? Wq : z == 1 ? Wk : z == 2 ? Wv : Wo;
    short* out = Wt + (size_t)z * DMODEL * DMODEL;
    int k0 = x * 64, n0 = y * 64;
#pragma unroll
    for (int i = 0; i < 4; ++i) {
      int idx = t + i * 256, row = idx >> 4, c4 = idx & 15;
      f32x4 v = *(const f32x4*)(W + (size_t)(k0 + row) * DMODEL + n0 + c4 * 4);
      s16x4 p;
      p[0] = f2bf(v[0]); p[1] = f2bf(v[1]); p[2] = f2bf(v[2]); p[3] = f2bf(v[3]);
      *(s16x4*)&tile[row][c4 * 4] = p;
    }
    __syncthreads();
#pragma unroll
    for (int i = 0; i < 2; ++i) {
      int idx = t + i * 256, nrow = idx >> 3, c8 = idx & 7;
      s16x8 p;
#pragma unroll
      for (int j = 0; j < 8; ++j) p[j] = tile[c8 * 8 + j][nrow];
      *(s16x8*)(out + (size_t)(n0 + nrow) * DMODEL + k0 + c8 * 8) = p;
    }
  } else if (bid < 7168) {
    int r = bid - 1024;
    int sel = r >> 11, bx = r & 2047;
    const float* src = sel == 0 ? Xq : sel == 1 ? Xk : Xv;
    size_t off = ((size_t)bx * 256 + t) * 8;
    f32x4 v0 = *(const f32x4*)(src + off);
    f32x4 v1 = *(const f32x4*)(src + off + 4);
    s16x8 p;
    p[0] = f2bf(v0[0]); p[1] = f2bf(v0[1]); p[2] = f2bf(v0[2]); p[3] = f2bf(v0[3]);
    p[4] = f2bf(v1[0]); p[5] = f2bf(v1[1]); p[6] = f2bf(v1[2]); p[7] = f2bf(v1[3]);
    *(s16x8*)(Xb + (size_t)sel * NTOK * DMODEL + off) = p;
  } else {
    int bx = bid - 7168;
    const int total_words = BATCH * SEQ * (SEQ / 64);
    int lane = t & 63;
    int wv = bx * 4 + (t >> 6);
    for (int w = wv; w < total_words; w += 4096) {
      int mv = mask[(size_t)w * 64 + lane];
      unsigned long long bits = __ballot(mv != 0);
      if (lane == 0) Mp[w] = bits;
    }
  }
}

// ---------------------------------------------------------------------------
// QKV projection: Xb bf16 @ Wt^T + b -> bf16.  3-buffer counted-vmcnt
// pipeline, 1 raw barrier/K-step, XCD-swizzled (768 = 8 x 96).
// Q,K -> [bh][s][d] (Q pre-scaled); V -> [bh][d][s].  grid 768, block 256.
// ---------------------------------------------------------------------------
__global__ __launch_bounds__(256) void proj_qkv_kernel(
    const short* __restrict__ Xb, const short* __restrict__ Wt,
    const float* __restrict__ bq, const float* __restrict__ bk,
    const float* __restrict__ bv, short* __restrict__ QKV) {
  __shared__ short As[3][128 * 32];
  __shared__ short Bs[3][128 * 32];
  int wg = blockIdx.x;
  int orig = (wg & 7) * 96 + (wg >> 3);
  int sel = orig >> 8;
  int rem = orig & 255;
  int mx = rem >> 3, ny = rem & 7;

  const short* X    = Xb + (size_t)sel * NTOK * DMODEL;
  const float* bias = sel == 0 ? bq : sel == 1 ? bk : bv;
  const short* Wsel = Wt + (size_t)sel * DMODEL * DMODEL;
  short* Obuf = QKV + (size_t)sel * ((size_t)BATCH * NHEAD * SEQ * DHEAD);
  const float scale = sel == 0 ? 0.18033688011111793f : 1.0f;  // (1/8)*log2e

  int m0 = mx * 128, n0 = ny * 128;
  int t = threadIdx.x, wid = t >> 6, lane = t & 63;
  int lr = lane & 15, lg = lane >> 4;
  int wr = wid >> 1, wc = wid & 1;
  f32x4 acc[4][4] = {};

  const int gr0 = t >> 2, gc0 = (t & 3) << 3;
  const short* Ax0 = X + (size_t)(m0 + gr0) * DMODEL + gc0;
  const short* Ax1 = Ax0 + (size_t)64 * DMODEL;
  const short* Bw0 = Wsel + (size_t)(n0 + gr0) * DMODEL + gc0;
  const short* Bw1 = Bw0 + (size_t)64 * DMODEL;
  const int lofs0 = (t & ~63) << 3, lofs1 = lofs0 + 256 * 8;

#define STAGEQ(bufi, k0s) {                                                   \
    gload_lds16(Ax0 + (k0s), &As[bufi][0] + lofs0);                           \
    gload_lds16(Ax1 + (k0s), &As[bufi][0] + lofs1);                           \
    gload_lds16(Bw0 + (k0s), &Bs[bufi][0] + lofs0);                           \
    gload_lds16(Bw1 + (k0s), &Bs[bufi][0] + lofs1); }

  STAGEQ(0, 0);
  STAGEQ(1, 32);

  int cb = 0;
  for (int kt = 0; kt < 32; ++kt) {
    if (kt + 1 < 32) { asm volatile("s_waitcnt vmcnt(4)" ::: "memory"); }
    else             { asm volatile("s_waitcnt vmcnt(0)" ::: "memory"); }
    __builtin_amdgcn_sched_barrier(0);
    __builtin_amdgcn_s_barrier();
    __builtin_amdgcn_sched_barrier(0);
    int st = cb + 2; if (st > 2) st -= 3;
    if (kt + 2 < 32) STAGEQ(st, (kt + 2) * 32);

    s16x8 afr[4], bfr[4];
#pragma unroll
    for (int mi = 0; mi < 4; ++mi)
      afr[mi] = *(const s16x8*)(&As[cb][0] + (wr * 64 + mi * 16 + lr) * 32 + lg * 8);
#pragma unroll
    for (int ni = 0; ni < 4; ++ni)
      bfr[ni] = *(const s16x8*)(&Bs[cb][0] + (wc * 64 + ni * 16 + lr) * 32 + lg * 8);
    __builtin_amdgcn_s_setprio(1);
#pragma unroll
    for (int mi = 0; mi < 4; ++mi)
#pragma unroll
      for (int ni = 0; ni < 4; ++ni)
        acc[mi][ni] = __builtin_amdgcn_mfma_f32_16x16x32_bf16(
            afr[mi], bfr[ni], acc[mi][ni], 0, 0, 0);
    __builtin_amdgcn_s_setprio(0);
    cb = (cb == 2) ? 0 : cb + 1;
  }
#undef STAGEQ

  if (sel == 2) {
    int bq_ = m0 >> 11;
    int s0 = (m0 & (SEQ - 1)) + wr * 64 + lg * 4;
#pragma unroll
    for (int mi = 0; mi < 4; ++mi)
#pragma unroll
      for (int ni = 0; ni < 4; ++ni) {
        int n = n0 + wc * 64 + ni * 16 + lr;
        float bv_ = bias[n];
        int h = n >> 6, d = n & 63;
        s16x4 pk;
#pragma unroll
        for (int r = 0; r < 4; ++r) pk[r] = f2bf(acc[mi][ni][r] + bv_);
        *(s16x4*)&Obuf[((size_t)(bq_ * NHEAD + h) * DHEAD + d) * SEQ
                       + s0 + mi * 16] = pk;
      }
  } else {
#pragma unroll
    for (int mi = 0; mi < 4; ++mi)
#pragma unroll
      for (int ni = 0; ni < 4; ++ni) {
        int n = n0 + wc * 64 + ni * 16 + lr;
        float bv_ = bias[n];
        int h = n >> 6, d = n & 63;
#pragma unroll
        for (int r = 0; r < 4; ++r) {
          int m = m0 + wr * 64 + mi * 16 + lg * 4 + r;
          int b = m >> 11, s = m & (SEQ - 1);
          float val = (acc[mi][ni][r] + bv_) * scale;
          Obuf[((size_t)(b * NHEAD + h) * SEQ + s) * DHEAD + d] = f2bf(val);
        }
      }
  }
}

// ---------------------------------------------------------------------------
// Flash attention, 32x32 swapped QK^T, in-register softmax, skewed PV.
// r20: 128-key staging GROUPS (2 sub-tiles per barrier) — barriers 32->16,
// 2x latency-hiding window per stage.  Per-sub-tile body identical to the
// r19 keeper.  2-buffer LDS (64KB); grid 512 (8x64 XCD swizzle), block 256.
// K LDS [128][64] (chunk c ^= key&7); V LDS [64][128] (chunk16 =
// (c&8)|((c&7)^(d&7)) — involution, staged via pre-swizzled source).
// ---------------------------------------------------------------------------
__global__ __launch_bounds__(256) void attn_kernel(
    const short* __restrict__ Qb, const short* __restrict__ Kb,
    const short* __restrict__ VbT, const unsigned long long* __restrict__ Mp,
    short* __restrict__ Ctx) {
  __shared__ short Ks[2][128 * 64];
  __shared__ short Vt[2][64 * 128];
  int wg = blockIdx.x;
  int orig = (wg & 7) * 64 + (wg >> 3);    // bijective: 512 = 8 x 64
  int bh = orig >> 4, qt = orig & 15;
  int b = bh >> 4, h = bh & 15;
  int q0 = qt * 128;
  int t = threadIdx.x, wid = t >> 6, lane = t & 63;
  int ql = lane & 31, hi = lane >> 5;
  int qrow = q0 + wid * 32 + ql;

  const short* Qp = Qb + ((size_t)bh * SEQ + qrow) * DHEAD + hi * 8;
  s16x8 qf[4];
#pragma unroll
  for (int ds = 0; ds < 4; ++ds) qf[ds] = *(const s16x8*)(Qp + ds * 16);

  const short* KbB = Kb + (size_t)bh * SEQ * DHEAD;    // [key][d]
  const short* VtB = VbT + (size_t)bh * DHEAD * SEQ;   // [d][key]

  // K staging: wave issue covers 8 rows x 8 chunks (1KB); src chunk ^= row&7.
  const int srowK = lane >> 3;
  const int schunkK = ((lane & 7) ^ srowK) * 8;
  // V staging: wave issue covers 4 rows x 16 chunks; row&7 = (i&1)*4 + srow4.
  const int srow4 = lane >> 4;

  // read offsets (sub-tile su adds: K su*4096, V su*64)
  int offK[4];
#pragma unroll
  for (int j = 0; j < 4; ++j)
    offK[j] = ql * 64 + (((j * 2 + hi) ^ (ql & 7)) << 3);
  int offVa[4], offVb[4];
#pragma unroll
  for (int m = 0; m < 4; ++m) {
    offVa[m] = ql * 128 + (((m * 2)     ^ (ql & 7)) << 3) + 4 * hi;
    offVb[m] = ql * 128 + (((m * 2 + 1) ^ (ql & 7)) << 3) + 4 * hi;
  }

  float m_run = -1e30f, l_run = 0.f;   // l_run = OWN-HALF partial sum
  f32x16 oacc0 = {}, oacc1 = {};
  s16x8 pPack[4];                      // P(prev sub-tile) fragments
  s16x8 vA[4], vB[4];                  // V(prev sub-tile) fragments

  const unsigned long long* mrow = Mp + ((size_t)b * SEQ + qrow) * (SEQ / 64);

#define STAGE128(bufi, grp)                                                   \
  {                                                                           \
    _Pragma("unroll")                                                         \
    for (int i = 0; i < 4; ++i) {                                             \
      int krb = wid * 32 + i * 8;                                             \
      gload_lds16(KbB + (size_t)((grp) * 128 + krb + srowK) * DHEAD + schunkK,\
                  &Ks[bufi][krb * 64]);                                       \
      int vrb = wid * 16 + i * 4;                                             \
      int vrow7 = ((i & 1) << 2) + srow4;                                     \
      int vch = (lane & 8) | ((lane & 7) ^ vrow7);                            \
      gload_lds16(VtB + (size_t)(vrb + srow4) * SEQ + (grp) * 128 + vch * 8,  \
                  &Vt[bufi][vrb * 128]);                                      \
    }                                                                         \
  }

  STAGE128(0, 0);

  int cb = 0;
  for (int g = 0; g < 16; ++g) {
    asm volatile("s_waitcnt vmcnt(0)" ::: "memory");   // group g landed
    __builtin_amdgcn_sched_barrier(0);
    __builtin_amdgcn_s_barrier();
    __builtin_amdgcn_sched_barrier(0);
    if (g + 1 < 16) STAGE128(cb ^ 1, g + 1);           // 2-subtile window
    unsigned long long mwA = mrow[2 * g];
    unsigned long long mwB = mrow[2 * g + 1];

    const short* KsC = Ks[cb];
    const short* VtC = Vt[cb];

#pragma unroll
    for (int su = 0; su < 2; ++su) {
      const short* KsS = KsC + su * 4096;
      const short* VtS = VtC + su * 64;
      unsigned long long mw_cur = su ? mwB : mwA;

      // QK^T(sub-tile)
      f32x16 sf0 = {}, sf1 = {};
      __builtin_amdgcn_s_setprio(1);
#pragma unroll
      for (int ds = 0; ds < 4; ++ds) {
        s16x8 k0 = *(const s16x8*)&KsS[offK[ds]];
        s16x8 k1 = *(const s16x8*)&KsS[offK[ds] + 2048];
        sf0 = __builtin_amdgcn_mfma_f32_32x32x16_bf16(k0, qf[ds], sf0, 0, 0, 0);
        sf1 = __builtin_amdgcn_mfma_f32_32x32x16_bf16(k1, qf[ds], sf1, 0, 0, 0);
      }
      // PV(prev sub-tile): pure-reg MFMAs under softmax VALU
      if (g > 0 || su == 1) {
#pragma unroll
        for (int m = 0; m < 4; ++m) {
          oacc0 = __builtin_amdgcn_mfma_f32_32x32x16_bf16(pPack[m], vA[m], oacc0, 0, 0, 0);
          oacc1 = __builtin_amdgcn_mfma_f32_32x32x16_bf16(pPack[m], vB[m], oacc1, 0, 0, 0);
        }
      }
      __builtin_amdgcn_s_setprio(0);

      // V fragments of THIS sub-tile (consumed by PV next sub-tile)
#pragma unroll
      for (int m = 0; m < 4; ++m) {
        union { s16x4 q[2]; s16x8 v; } v0, v1;
        v0.q[0] = *(const s16x4*)&VtS[offVa[m]];
        v0.q[1] = *(const s16x4*)&VtS[offVb[m]];
        v1.q[0] = *(const s16x4*)&VtS[offVa[m] + 4096];   // +32 d-rows
        v1.q[1] = *(const s16x4*)&VtS[offVb[m] + 4096];
        vA[m] = v0.v;
        vB[m] = v1.v;
      }

      // softmax — identical to r19 keeper
      unsigned h0 = ((unsigned)mw_cur) >> (hi << 2);
      unsigned h1 = ((unsigned)(mw_cur >> 32)) >> (hi << 2);
#pragma unroll
      for (int r = 0; r < 16; ++r) {
        const int c = (r & 3) + 8 * (r >> 2);
        if ((h0 >> c) & 1u) sf0[r] = -1e30f;
        if ((h1 >> c) & 1u) sf1[r] = -1e30f;
      }
      float tm = sf0[0];
#pragma unroll
      for (int r = 1; r < 16; ++r) tm = fmaxf(tm, sf0[r]);
#pragma unroll
      for (int r = 0; r < 16; ++r) tm = fmaxf(tm, sf1[r]);

      bool small = __all(tm <= m_run + 8.0f);
      if (!small) {
        float tmx = fmaxf(tm, __shfl_xor(tm, 32, 64));   // rare path only
        float mnew = fmaxf(m_run, tmx);
        float scl = __builtin_amdgcn_exp2f(m_run - mnew);
        m_run = mnew;
        l_run *= scl;
#pragma unroll
        for (int r = 0; r < 16; ++r) {
          float s_ = __shfl(scl, (r & 3) + 8 * (r >> 2) + 4 * hi, 64);
          oacc0[r] *= s_;
          oacc1[r] *= s_;
        }
      }

      float ss = 0.f;
#pragma unroll
      for (int r = 0; r < 16; ++r) {
        sf0[r] = __builtin_amdgcn_exp2f(sf0[r] - m_run);
        sf1[r] = __builtin_amdgcn_exp2f(sf1[r] - m_run);
        ss += sf0[r] + sf1[r];
      }
      l_run += ss;

      // pack P(sub-tile) for next PV (native D-layout slots)
#pragma unroll
      for (int m = 0; m < 4; ++m) {
        const int base = (m & 1) * 8;
        s16x8 pa;
#pragma unroll
        for (int e = 0; e < 8; ++e)
          pa[e] = f2bf(m < 2 ? sf0[base + e] : sf1[base + e]);
        pPack[m] = pa;
      }
    }

    // V-reg ds_reads must land before next iter's STAGE overwrites buf cb
    asm volatile("s_waitcnt lgkmcnt(0)" ::: "memory");
    __builtin_amdgcn_sched_barrier(0);
    cb ^= 1;
  }
#undef STAGE128

  // final PV (last sub-tile)
  __builtin_amdgcn_s_setprio(1);
#pragma unroll
  for (int m = 0; m < 4; ++m) {
    oacc0 = __builtin_amdgcn_mfma_f32_32x32x16_bf16(pPack[m], vA[m], oacc0, 0, 0, 0);
    oacc1 = __builtin_amdgcn_mfma_f32_32x32x16_bf16(pPack[m], vB[m], oacc1, 0, 0, 0);
  }
  __builtin_amdgcn_s_setprio(0);

  // epilogue: merge half-sums, divide (oacc[r]: q'=crow(r,hi), d=ql)
  float l_tot = l_run + __shfl_xor(l_run, 32, 64);
#pragma unroll
  for (int r = 0; r < 16; ++r) {
    int c = (r & 3) + 8 * (r >> 2) + 4 * hi;
    float linv = 1.0f / __shfl(l_tot, c, 64);
    int q_ = q0 + wid * 32 + c;
    size_t base = ((size_t)b * SEQ + q_) * DMODEL + h * DHEAD + ql;
    Ctx[base] = f2bf(oacc0[r] * linv);
    Ctx[base + 32] = f2bf(oacc1[r] * linv);
  }
}

// ---------------------------------------------------------------------------
// Output projection: ctx bf16 @ Wo + bo -> fp32 out.  3-buffer counted-vmcnt
// pipeline, XCD-swizzled (256 = 8 x 32).  grid 256, block 256.
// ---------------------------------------------------------------------------
__global__ __launch_bounds__(256) void proj_out_kernel(
    const short* __restrict__ Ctx, const short* __restrict__ Wot,
    const float* __restrict__ bo, float* __restrict__ Out) {
  __shared__ short As[3][128 * 32];
  __shared__ short Bs[3][128 * 32];
  int wg = blockIdx.x;
  int orig = (wg & 7) * 32 + (wg >> 3);
  int mx = orig >> 3, ny = orig & 7;
  int m0 = mx * 128, n0 = ny * 128;
  int t = threadIdx.x, wid = t >> 6, lane = t & 63;
  int lr = lane & 15, lg = lane >> 4;
  int wr = wid >> 1, wc = wid & 1;
  f32x4 acc[4][4] = {};

  const int gr0 = t >> 2, gc0 = (t & 3) << 3;
  const short* Actx0 = Ctx + (size_t)(m0 + gr0) * DMODEL + gc0;
  const short* Actx1 = Actx0 + (size_t)64 * DMODEL;
  const short* Bwo0 = Wot + (size_t)(n0 + gr0) * DMODEL + gc0;
  const short* Bwo1 = Bwo0 + (size_t)64 * DMODEL;
  const int lofs0 = (t & ~63) << 3, lofs1 = lofs0 + 256 * 8;

#define STAGE_PO(bufi, k0s) {                                                 \
    gload_lds16(Actx0 + (k0s), &As[bufi][0] + lofs0);                         \
    gload_lds16(Actx1 + (k0s), &As[bufi][0] + lofs1);                         \
    gload_lds16(Bwo0 + (k0s), &Bs[bufi][0] + lofs0);                         \
    gload_lds16(Bwo1 + (k0s), &Bs[bufi][0] + lofs1); }

  STAGE_PO(0, 0);
  STAGE_PO(1, 32);

  int cb = 0;
  for (int kt = 0; kt < 32; ++kt) {
    if (kt + 1 < 32) { asm volatile("s_waitcnt vmcnt(4)" ::: "memory"); }
    else             { asm volatile("s_waitcnt vmcnt(0)" ::: "memory"); }
    __builtin_amdgcn_sched_barrier(0);
    __builtin_amdgcn_s_barrier();
    __builtin_amdgcn_sched_barrier(0);
    int st = cb + 2; if (st > 2) st -= 3;
    if (kt + 2 < 32) STAGE_PO(st, (kt + 2) * 32);

    s16x8 afr[4], bfr[4];
#pragma unroll
    for (int mi = 0; mi < 4; ++mi)
      afr[mi] = *(const s16x8*)(&As[cb][0] + (wr * 64 + mi * 16 + lr) * 32 + lg * 8);
#pragma unroll
    for (int ni = 0; ni < 4; ++ni)
      bfr[ni] = *(const s16x8*)(&Bs[cb][0] + (wc * 64 + ni * 16 + lr) * 32 + lg * 8);
    __builtin_amdgcn_s_setprio(1);
#pragma unroll
    for (int mi = 0; mi < 4; ++mi)
#pragma unroll
      for (int ni = 0; ni < 4; ++ni)
        acc[mi][ni] = __builtin_amdgcn_mfma_f32_16x16x32_bf16(
            afr[mi], bfr[ni], acc[mi][ni], 0, 0, 0);
    __builtin_amdgcn_s_setprio(0);
    cb = (cb == 2) ? 0 : cb + 1;
  }
#undef STAGE_PO

#pragma unroll
  for (int mi = 0; mi < 4; ++mi)
#pragma unroll
    for (int ni = 0; ni < 4; ++ni) {
      int n = n0 + wc * 64 + ni * 16 + lr;
      float bv_ = bo[n];
#pragma unroll
      for (int r = 0; r < 4; ++r) {
        int m = m0 + wr * 64 + mi * 16 + lg * 4 + r;
        Out[(size_t)m * DMODEL + n] = acc[mi][ni][r] + bv_;
      }
    }
}

// ---------------------------------------------------------------------------
extern "C" void kernel_launch(void* const* d_in, const int* in_sizes, int n_in,
                              void* d_out, int out_size, void* d_ws, size_t ws_size,
                              hipStream_t stream) {
  const float* key_in   = (const float*)d_in[0];
  const float* value_in = (const float*)d_in[1];
  const float* query_in = (const float*)d_in[2];
  const int*   mask     = (const int*)d_in[3];
  const float* Wq = (const float*)d_in[4];
  const float* bq = (const float*)d_in[5];
  const float* Wk = (const float*)d_in[6];
  const float* bk = (const float*)d_in[7];
  const float* Wv = (const float*)d_in[8];
  const float* bv = (const float*)d_in[9];
  const float* Wo = (const float*)d_in[10];
  const float* bo = (const float*)d_in[11];
  float* out = (float*)d_out;

  short* ws = (short*)d_ws;
  const size_t WSZ   = (size_t)DMODEL * DMODEL;              // 1M elems
  const size_t QKVSZ = (size_t)BATCH * NHEAD * SEQ * DHEAD;  // 4M elems
  short* Wt  = ws;                         // [0, 4M)   4 weights bf16
  short* QKV = ws + 4 * WSZ;               // Q [4M,8M) K [8M,12M) V^T [12M,16M)
  short* Qb  = QKV;
  short* Kb  = QKV + QKVSZ;
  short* VbT = QKV + 2 * QKVSZ;            // [bh][d][s]
  short* Xb  = ws + 4 * WSZ + 3 * QKVSZ;   // [16M, 28M)  bf16 activations
  short* Ctx = Xb;                         // overlays Xb[query] (dead by attn)
  // Mp lives in d_out (1MB << 16MB): written by prep, consumed by attn,
  // fully overwritten by proj_out afterwards (stream-serial, capture-safe).
  unsigned long long* Mp = (unsigned long long*)d_out;

  prep_kernel<<<dim3(8192), 256, 0, stream>>>(
      Wq, Wk, Wv, Wo, Wt, query_in, key_in, value_in, Xb, mask, Mp);
  proj_qkv_kernel<<<dim3(768), 256, 0, stream>>>(Xb, Wt, bq, bk, bv, QKV);
  attn_kernel<<<dim3(512), 256, 0, stream>>>(Qb, Kb, VbT, Mp, Ctx);
  proj_out_kernel<<<dim3(256), 256, 0, stream>>>(Ctx, Wt + 3 * WSZ, bo, out);
}

// Round 21
// 162.667 us; speedup vs baseline: 1.1481x; 1.1481x over previous
//
#include <hip/hip_runtime.h>
#include <hip/hip_bf16.h>

#define BATCH  2
#define SEQ    2048
#define DMODEL 1024
#define NHEAD  16
#define DHEAD  64
#define NTOK   (BATCH * SEQ)

using f32x4  = __attribute__((ext_vector_type(4))) float;
using f32x16 = __attribute__((ext_vector_type(16))) float;
using s16x4  = __attribute__((ext_vector_type(4))) short;
using s16x8  = __attribute__((ext_vector_type(8))) short;

__device__ __forceinline__ short f2bf(float f) {
  __hip_bfloat16 h = __float2bfloat16(f);
  return *(short*)&h;
}

__device__ __forceinline__ void gload_lds16(const short* g, short* l) {
  __builtin_amdgcn_global_load_lds(
      (const __attribute__((address_space(1))) void*)g,
      (__attribute__((address_space(3))) void*)l, 16, 0, 0);
}

// ---------------------------------------------------------------------------
// prep: fused wtrans (blocks 0..1023) | xcast (1024..7167) | mpack (7168..8191)
// ---------------------------------------------------------------------------
__global__ __launch_bounds__(256) void prep_kernel(
    const float* __restrict__ Wq, const float* __restrict__ Wk,
    const float* __restrict__ Wv, const float* __restrict__ Wo,
    short* __restrict__ Wt,
    const float* __restrict__ Xq, const float* __restrict__ Xk,
    const float* __restrict__ Xv, short* __restrict__ Xb,
    const int* __restrict__ mask, unsigned long long* __restrict__ Mp) {
  __shared__ short tile[64][72];
  int bid = blockIdx.x, t = threadIdx.x;
  if (bid < 1024) {
    int z = bid >> 8, rem = bid & 255, x = rem & 15, y = rem >> 4;
    const float* W = z == 0 ? Wq : z == 1 ? Wk : z == 2 ? Wv : Wo;
    short* out = Wt + (size_t)z * DMODEL * DMODEL;
    int k0 = x * 64, n0 = y * 64;
#pragma unroll
    for (int i = 0; i < 4; ++i) {
      int idx = t + i * 256, row = idx >> 4, c4 = idx & 15;
      f32x4 v = *(const f32x4*)(W + (size_t)(k0 + row) * DMODEL + n0 + c4 * 4);
      s16x4 p;
      p[0] = f2bf(v[0]); p[1] = f2bf(v[1]); p[2] = f2bf(v[2]); p[3] = f2bf(v[3]);
      *(s16x4*)&tile[row][c4 * 4] = p;
    }
    __syncthreads();
#pragma unroll
    for (int i = 0; i < 2; ++i) {
      int idx = t + i * 256, nrow = idx >> 3, c8 = idx & 7;
      s16x8 p;
#pragma unroll
      for (int j = 0; j < 8; ++j) p[j] = tile[c8 * 8 + j][nrow];
      *(s16x8*)(out + (size_t)(n0 + nrow) * DMODEL + k0 + c8 * 8) = p;
    }
  } else if (bid < 7168) {
    int r = bid - 1024;
    int sel = r >> 11, bx = r & 2047;
    const float* src = sel == 0 ? Xq : sel == 1 ? Xk : Xv;
    size_t off = ((size_t)bx * 256 + t) * 8;
    f32x4 v0 = *(const f32x4*)(src + off);
    f32x4 v1 = *(const f32x4*)(src + off + 4);
    s16x8 p;
    p[0] = f2bf(v0[0]); p[1] = f2bf(v0[1]); p[2] = f2bf(v0[2]); p[3] = f2bf(v0[3]);
    p[4] = f2bf(v1[0]); p[5] = f2bf(v1[1]); p[6] = f2bf(v1[2]); p[7] = f2bf(v1[3]);
    *(s16x8*)(Xb + (size_t)sel * NTOK * DMODEL + off) = p;
  } else {
    int bx = bid - 7168;
    const int total_words = BATCH * SEQ * (SEQ / 64);
    int lane = t & 63;
    int wv = bx * 4 + (t >> 6);
    for (int w = wv; w < total_words; w += 4096) {
      int mv = mask[(size_t)w * 64 + lane];
      unsigned long long bits = __ballot(mv != 0);
      if (lane == 0) Mp[w] = bits;
    }
  }
}

// ---------------------------------------------------------------------------
// QKV projection: Xb bf16 @ Wt^T + b -> bf16.  3-buffer counted-vmcnt
// pipeline, 1 raw barrier/K-step, XCD-swizzled (768 = 8 x 96).
// Q,K -> [bh][s][d] (Q pre-scaled); V -> [bh][d][s].  grid 768, block 256.
// ---------------------------------------------------------------------------
__global__ __launch_bounds__(256) void proj_qkv_kernel(
    const short* __restrict__ Xb, const short* __restrict__ Wt,
    const float* __restrict__ bq, const float* __restrict__ bk,
    const float* __restrict__ bv, short* __restrict__ QKV) {
  __shared__ short As[3][128 * 32];
  __shared__ short Bs[3][128 * 32];
  int wg = blockIdx.x;
  int orig = (wg & 7) * 96 + (wg >> 3);
  int sel = orig >> 8;
  int rem = orig & 255;
  int mx = rem >> 3, ny = rem & 7;

  const short* X    = Xb + (size_t)sel * NTOK * DMODEL;
  const float* bias = sel == 0 ? bq : sel == 1 ? bk : bv;
  const short* Wsel = Wt + (size_t)sel * DMODEL * DMODEL;
  short* Obuf = QKV + (size_t)sel * ((size_t)BATCH * NHEAD * SEQ * DHEAD);
  const float scale = sel == 0 ? 0.18033688011111793f : 1.0f;  // (1/8)*log2e

  int m0 = mx * 128, n0 = ny * 128;
  int t = threadIdx.x, wid = t >> 6, lane = t & 63;
  int lr = lane & 15, lg = lane >> 4;
  int wr = wid >> 1, wc = wid & 1;
  f32x4 acc[4][4] = {};

  const int gr0 = t >> 2, gc0 = (t & 3) << 3;
  const short* Ax0 = X + (size_t)(m0 + gr0) * DMODEL + gc0;
  const short* Ax1 = Ax0 + (size_t)64 * DMODEL;
  const short* Bw0 = Wsel + (size_t)(n0 + gr0) * DMODEL + gc0;
  const short* Bw1 = Bw0 + (size_t)64 * DMODEL;
  const int lofs0 = (t & ~63) << 3, lofs1 = lofs0 + 256 * 8;

#define STAGEQ(bufi, k0s) {                                                   \
    gload_lds16(Ax0 + (k0s), &As[bufi][0] + lofs0);                           \
    gload_lds16(Ax1 + (k0s), &As[bufi][0] + lofs1);                           \
    gload_lds16(Bw0 + (k0s), &Bs[bufi][0] + lofs0);                           \
    gload_lds16(Bw1 + (k0s), &Bs[bufi][0] + lofs1); }

  STAGEQ(0, 0);
  STAGEQ(1, 32);

  int cb = 0;
  for (int kt = 0; kt < 32; ++kt) {
    if (kt + 1 < 32) { asm volatile("s_waitcnt vmcnt(4)" ::: "memory"); }
    else             { asm volatile("s_waitcnt vmcnt(0)" ::: "memory"); }
    __builtin_amdgcn_sched_barrier(0);
    __builtin_amdgcn_s_barrier();
    __builtin_amdgcn_sched_barrier(0);
    int st = cb + 2; if (st > 2) st -= 3;
    if (kt + 2 < 32) STAGEQ(st, (kt + 2) * 32);

    s16x8 afr[4], bfr[4];
#pragma unroll
    for (int mi = 0; mi < 4; ++mi)
      afr[mi] = *(const s16x8*)(&As[cb][0] + (wr * 64 + mi * 16 + lr) * 32 + lg * 8);
#pragma unroll
    for (int ni = 0; ni < 4; ++ni)
      bfr[ni] = *(const s16x8*)(&Bs[cb][0] + (wc * 64 + ni * 16 + lr) * 32 + lg * 8);
    __builtin_amdgcn_s_setprio(1);
#pragma unroll
    for (int mi = 0; mi < 4; ++mi)
#pragma unroll
      for (int ni = 0; ni < 4; ++ni)
        acc[mi][ni] = __builtin_amdgcn_mfma_f32_16x16x32_bf16(
            afr[mi], bfr[ni], acc[mi][ni], 0, 0, 0);
    __builtin_amdgcn_s_setprio(0);
    cb = (cb == 2) ? 0 : cb + 1;
  }
#undef STAGEQ

  if (sel == 2) {
    int bq_ = m0 >> 11;
    int s0 = (m0 & (SEQ - 1)) + wr * 64 + lg * 4;
#pragma unroll
    for (int mi = 0; mi < 4; ++mi)
#pragma unroll
      for (int ni = 0; ni < 4; ++ni) {
        int n = n0 + wc * 64 + ni * 16 + lr;
        float bv_ = bias[n];
        int h = n >> 6, d = n & 63;
        s16x4 pk;
#pragma unroll
        for (int r = 0; r < 4; ++r) pk[r] = f2bf(acc[mi][ni][r] + bv_);
        *(s16x4*)&Obuf[((size_t)(bq_ * NHEAD + h) * DHEAD + d) * SEQ
                       + s0 + mi * 16] = pk;
      }
  } else {
#pragma unroll
    for (int mi = 0; mi < 4; ++mi)
#pragma unroll
      for (int ni = 0; ni < 4; ++ni) {
        int n = n0 + wc * 64 + ni * 16 + lr;
        float bv_ = bias[n];
        int h = n >> 6, d = n & 63;
#pragma unroll
        for (int r = 0; r < 4; ++r) {
          int m = m0 + wr * 64 + mi * 16 + lg * 4 + r;
          int b = m >> 11, s = m & (SEQ - 1);
          float val = (acc[mi][ni][r] + bv_) * scale;
          Obuf[((size_t)(b * NHEAD + h) * SEQ + s) * DHEAD + d] = f2bf(val);
        }
      }
  }
}

// ---------------------------------------------------------------------------
// Flash attention, 32x32 swapped QK^T, in-register softmax, SKEWED pipeline
// (best-measured config): iter t issues QK^T(t) then PV(t-1) from regs so
// softmax(t) VALU overlaps the matrix pipe.  3-buffer counted-vmcnt staging;
// grid 512 (8x64 XCD swizzle), block 256.
// ---------------------------------------------------------------------------
__global__ __launch_bounds__(256) void attn_kernel(
    const short* __restrict__ Qb, const short* __restrict__ Kb,
    const short* __restrict__ VbT, const unsigned long long* __restrict__ Mp,
    short* __restrict__ Ctx) {
  __shared__ short Ks[3][64 * 64];    // [key][d], 16B-chunk c ^= key&7
  __shared__ short Vt[3][64 * 64];    // [d][key], chunk c ^= d&7
  int wg = blockIdx.x;
  int orig = (wg & 7) * 64 + (wg >> 3);    // bijective: 512 = 8 x 64
  int bh = orig >> 4, qt = orig & 15;
  int b = bh >> 4, h = bh & 15;
  int q0 = qt * 128;
  int t = threadIdx.x, wid = t >> 6, lane = t & 63;
  int ql = lane & 31, hi = lane >> 5;
  int qrow = q0 + wid * 32 + ql;

  const short* Qp = Qb + ((size_t)bh * SEQ + qrow) * DHEAD + hi * 8;
  s16x8 qf[4];
#pragma unroll
  for (int ds = 0; ds < 4; ++ds) qf[ds] = *(const s16x8*)(Qp + ds * 16);

  const short* KbB = Kb + (size_t)bh * SEQ * DHEAD;    // [key][d]
  const short* VtB = VbT + (size_t)bh * DHEAD * SEQ;   // [d][key]

  const int srow = lane >> 3;
  const int schunk = ((lane & 7) ^ srow) * 8;

  int offK[4];
#pragma unroll
  for (int j = 0; j < 4; ++j)
    offK[j] = ql * 64 + (((j * 2 + hi) ^ (ql & 7)) << 3);
  int offVa[4], offVb[4];
#pragma unroll
  for (int m = 0; m < 4; ++m) {
    offVa[m] = ql * 64 + (((m * 2)     ^ (ql & 7)) << 3) + 4 * hi;
    offVb[m] = ql * 64 + (((m * 2 + 1) ^ (ql & 7)) << 3) + 4 * hi;
  }

  float m_run = -1e30f, l_run = 0.f;   // l_run = OWN-HALF partial sum
  f32x16 oacc0 = {}, oacc1 = {};
  s16x8 pPack[4];                      // P(t-1) bf16 fragments (native slots)
  s16x8 vA[4], vB[4];                  // V(t-1) fragments

  const unsigned long long* mrow = Mp + ((size_t)b * SEQ + qrow) * (SEQ / 64);

#define STAGE(bufi, k0s)                                                      \
  {                                                                           \
    _Pragma("unroll")                                                         \
    for (int i = 0; i < 2; ++i) {                                             \
      int rbase = wid * 16 + i * 8;                                           \
      gload_lds16(KbB + (size_t)((k0s) + rbase + srow) * DHEAD + schunk,      \
                  &Ks[bufi][rbase * 64]);                                     \
      gload_lds16(VtB + (size_t)(rbase + srow) * SEQ + (k0s) + schunk,        \
                  &Vt[bufi][rbase * 64]);                                     \
    }                                                                         \
  }

  unsigned long long mwq0 = mrow[0], mwq1 = mrow[1];
  STAGE(0, 0);
  STAGE(1, 64);

  int cb = 0;
  for (int kt = 0; kt < 32; ++kt) {
    if (kt + 1 < 32) { asm volatile("s_waitcnt vmcnt(4)" ::: "memory"); }
    else             { asm volatile("s_waitcnt vmcnt(0)" ::: "memory"); }
    __builtin_amdgcn_sched_barrier(0);
    __builtin_amdgcn_s_barrier();
    __builtin_amdgcn_sched_barrier(0);
    int st = cb + 2; if (st > 2) st -= 3;
    if (kt + 2 < 32) STAGE(st, (kt + 2) * 64);
    unsigned long long mw_cur = mwq0;
    mwq0 = mwq1;
    if (kt + 2 < 32) mwq1 = mrow[kt + 2];

    const short* KsC = Ks[cb];
    const short* VtC = Vt[cb];

    // QK^T(t): issue 16 MFMAs
    f32x16 sf0 = {}, sf1 = {};
    __builtin_amdgcn_s_setprio(1);
#pragma unroll
    for (int ds = 0; ds < 4; ++ds) {
      s16x8 k0 = *(const s16x8*)&KsC[offK[ds]];
      s16x8 k1 = *(const s16x8*)&KsC[offK[ds] + 2048];
      sf0 = __builtin_amdgcn_mfma_f32_32x32x16_bf16(k0, qf[ds], sf0, 0, 0, 0);
      sf1 = __builtin_amdgcn_mfma_f32_32x32x16_bf16(k1, qf[ds], sf1, 0, 0, 0);
    }
    // PV(t-1): pure-reg MFMAs queue behind QK^T; execute under softmax VALU
    if (kt > 0) {
#pragma unroll
      for (int m = 0; m < 4; ++m) {
        oacc0 = __builtin_amdgcn_mfma_f32_32x32x16_bf16(pPack[m], vA[m], oacc0, 0, 0, 0);
        oacc1 = __builtin_amdgcn_mfma_f32_32x32x16_bf16(pPack[m], vB[m], oacc1, 0, 0, 0);
      }
    }
    __builtin_amdgcn_s_setprio(0);

    // V fragments of THIS tile (used by PV at iter t+1) — issue reads early
#pragma unroll
    for (int m = 0; m < 4; ++m) {
      union { s16x4 q[2]; s16x8 v; } v0, v1;
      v0.q[0] = *(const s16x4*)&VtC[offVa[m]];
      v0.q[1] = *(const s16x4*)&VtC[offVb[m]];
      v1.q[0] = *(const s16x4*)&VtC[offVa[m] + 2048];
      v1.q[1] = *(const s16x4*)&VtC[offVb[m] + 2048];
      vA[m] = v0.v;
      vB[m] = v1.v;
    }

    // softmax(t) — overlaps the queued MFMAs
    unsigned h0 = ((unsigned)mw_cur) >> (hi << 2);
    unsigned h1 = ((unsigned)(mw_cur >> 32)) >> (hi << 2);
#pragma unroll
    for (int r = 0; r < 16; ++r) {
      const int c = (r & 3) + 8 * (r >> 2);
      if ((h0 >> c) & 1u) sf0[r] = -1e30f;
      if ((h1 >> c) & 1u) sf1[r] = -1e30f;
    }
    float tm = sf0[0];
#pragma unroll
    for (int r = 1; r < 16; ++r) tm = fmaxf(tm, sf0[r]);
#pragma unroll
    for (int r = 0; r < 16; ++r) tm = fmaxf(tm, sf1[r]);

    bool small = __all(tm <= m_run + 8.0f);
    if (!small) {
      float tmx = fmaxf(tm, __shfl_xor(tm, 32, 64));   // rare path only
      float mnew = fmaxf(m_run, tmx);
      float scl = __builtin_amdgcn_exp2f(m_run - mnew);
      m_run = mnew;
      l_run *= scl;
      // reads oacc -> reg dependency forces PV(t-1) completion first: exact
#pragma unroll
      for (int r = 0; r < 16; ++r) {
        float s_ = __shfl(scl, (r & 3) + 8 * (r >> 2) + 4 * hi, 64);
        oacc0[r] *= s_;
        oacc1[r] *= s_;
      }
    }

    float ss = 0.f;
#pragma unroll
    for (int r = 0; r < 16; ++r) {
      sf0[r] = __builtin_amdgcn_exp2f(sf0[r] - m_run);
      sf1[r] = __builtin_amdgcn_exp2f(sf1[r] - m_run);
      ss += sf0[r] + sf1[r];
    }
    l_run += ss;

    // pack P(t) for next iter's PV (native D-layout slots — r9-verified)
#pragma unroll
    for (int m = 0; m < 4; ++m) {
      const int base = (m & 1) * 8;
      s16x8 pa;
#pragma unroll
      for (int e = 0; e < 8; ++e)
        pa[e] = f2bf(m < 2 ? sf0[base + e] : sf1[base + e]);
      pPack[m] = pa;
    }

    // V-reg reads must land before other waves overwrite buf cb (iter t+1)
    asm volatile("s_waitcnt lgkmcnt(0)" ::: "memory");
    __builtin_amdgcn_sched_barrier(0);
    cb = (cb == 2) ? 0 : cb + 1;
  }
#undef STAGE

  // final PV(31)
  __builtin_amdgcn_s_setprio(1);
#pragma unroll
  for (int m = 0; m < 4; ++m) {
    oacc0 = __builtin_amdgcn_mfma_f32_32x32x16_bf16(pPack[m], vA[m], oacc0, 0, 0, 0);
    oacc1 = __builtin_amdgcn_mfma_f32_32x32x16_bf16(pPack[m], vB[m], oacc1, 0, 0, 0);
  }
  __builtin_amdgcn_s_setprio(0);

  // epilogue: merge half-sums, divide (oacc[r]: q'=crow(r,hi), d=ql)
  float l_tot = l_run + __shfl_xor(l_run, 32, 64);
#pragma unroll
  for (int r = 0; r < 16; ++r) {
    int c = (r & 3) + 8 * (r >> 2) + 4 * hi;
    float linv = 1.0f / __shfl(l_tot, c, 64);
    int q_ = q0 + wid * 32 + c;
    size_t base = ((size_t)b * SEQ + q_) * DMODEL + h * DHEAD + ql;
    Ctx[base] = f2bf(oacc0[r] * linv);
    Ctx[base + 32] = f2bf(oacc1[r] * linv);
  }
}

// ---------------------------------------------------------------------------
// Output projection: ctx bf16 @ Wo + bo -> fp32 out.  3-buffer counted-vmcnt
// pipeline, XCD-swizzled (256 = 8 x 32).  grid 256, block 256.
// ---------------------------------------------------------------------------
__global__ __launch_bounds__(256) void proj_out_kernel(
    const short* __restrict__ Ctx, const short* __restrict__ Wot,
    const float* __restrict__ bo, float* __restrict__ Out) {
  __shared__ short As[3][128 * 32];
  __shared__ short Bs[3][128 * 32];
  int wg = blockIdx.x;
  int orig = (wg & 7) * 32 + (wg >> 3);
  int mx = orig >> 3, ny = orig & 7;
  int m0 = mx * 128, n0 = ny * 128;
  int t = threadIdx.x, wid = t >> 6, lane = t & 63;
  int lr = lane & 15, lg = lane >> 4;
  int wr = wid >> 1, wc = wid & 1;
  f32x4 acc[4][4] = {};

  const int gr0 = t >> 2, gc0 = (t & 3) << 3;
  const short* Actx0 = Ctx + (size_t)(m0 + gr0) * DMODEL + gc0;
  const short* Actx1 = Actx0 + (size_t)64 * DMODEL;
  const short* Bwo0 = Wot + (size_t)(n0 + gr0) * DMODEL + gc0;
  const short* Bwo1 = Bwo0 + (size_t)64 * DMODEL;
  const int lofs0 = (t & ~63) << 3, lofs1 = lofs0 + 256 * 8;

#define STAGE_PO(bufi, k0s) {                                                 \
    gload_lds16(Actx0 + (k0s), &As[bufi][0] + lofs0);                         \
    gload_lds16(Actx1 + (k0s), &As[bufi][0] + lofs1);                         \
    gload_lds16(Bwo0 + (k0s), &Bs[bufi][0] + lofs0);                          \
    gload_lds16(Bwo1 + (k0s), &Bs[bufi][0] + lofs1); }

  STAGE_PO(0, 0);
  STAGE_PO(1, 32);

  int cb = 0;
  for (int kt = 0; kt < 32; ++kt) {
    if (kt + 1 < 32) { asm volatile("s_waitcnt vmcnt(4)" ::: "memory"); }
    else             { asm volatile("s_waitcnt vmcnt(0)" ::: "memory"); }
    __builtin_amdgcn_sched_barrier(0);
    __builtin_amdgcn_s_barrier();
    __builtin_amdgcn_sched_barrier(0);
    int st = cb + 2; if (st > 2) st -= 3;
    if (kt + 2 < 32) STAGE_PO(st, (kt + 2) * 32);

    s16x8 afr[4], bfr[4];
#pragma unroll
    for (int mi = 0; mi < 4; ++mi)
      afr[mi] = *(const s16x8*)(&As[cb][0] + (wr * 64 + mi * 16 + lr) * 32 + lg * 8);
#pragma unroll
    for (int ni = 0; ni < 4; ++ni)
      bfr[ni] = *(const s16x8*)(&Bs[cb][0] + (wc * 64 + ni * 16 + lr) * 32 + lg * 8);
    __builtin_amdgcn_s_setprio(1);
#pragma unroll
    for (int mi = 0; mi < 4; ++mi)
#pragma unroll
      for (int ni = 0; ni < 4; ++ni)
        acc[mi][ni] = __builtin_amdgcn_mfma_f32_16x16x32_bf16(
            afr[mi], bfr[ni], acc[mi][ni], 0, 0, 0);
    __builtin_amdgcn_s_setprio(0);
    cb = (cb == 2) ? 0 : cb + 1;
  }
#undef STAGE_PO

#pragma unroll
  for (int mi = 0; mi < 4; ++mi)
#pragma unroll
    for (int ni = 0; ni < 4; ++ni) {
      int n = n0 + wc * 64 + ni * 16 + lr;
      float bv_ = bo[n];
#pragma unroll
      for (int r = 0; r < 4; ++r) {
        int m = m0 + wr * 64 + mi * 16 + lg * 4 + r;
        Out[(size_t)m * DMODEL + n] = acc[mi][ni][r] + bv_;
      }
    }
}

// ---------------------------------------------------------------------------
extern "C" void kernel_launch(void* const* d_in, const int* in_sizes, int n_in,
                              void* d_out, int out_size, void* d_ws, size_t ws_size,
                              hipStream_t stream) {
  const float* key_in   = (const float*)d_in[0];
  const float* value_in = (const float*)d_in[1];
  const float* query_in = (const float*)d_in[2];
  const int*   mask     = (const int*)d_in[3];
  const float* Wq = (const float*)d_in[4];
  const float* bq = (const float*)d_in[5];
  const float* Wk = (const float*)d_in[6];
  const float* bk = (const float*)d_in[7];
  const float* Wv = (const float*)d_in[8];
  const float* bv = (const float*)d_in[9];
  const float* Wo = (const float*)d_in[10];
  const float* bo = (const float*)d_in[11];
  float* out = (float*)d_out;

  short* ws = (short*)d_ws;
  const size_t WSZ   = (size_t)DMODEL * DMODEL;              // 1M elems
  const size_t QKVSZ = (size_t)BATCH * NHEAD * SEQ * DHEAD;  // 4M elems
  short* Wt  = ws;                         // [0, 4M)   4 weights bf16
  short* QKV = ws + 4 * WSZ;               // Q [4M,8M) K [8M,12M) V^T [12M,16M)
  short* Qb  = QKV;
  short* Kb  = QKV + QKVSZ;
  short* VbT = QKV + 2 * QKVSZ;            // [bh][d][s]
  short* Xb  = ws + 4 * WSZ + 3 * QKVSZ;   // [16M, 28M)  bf16 activations
  short* Ctx = Xb;                         // overlays Xb[query] (dead by attn)
  // Mp lives in d_out (1MB << 16MB): written by prep, consumed by attn,
  // fully overwritten by proj_out afterwards (stream-serial, capture-safe).
  unsigned long long* Mp = (unsigned long long*)d_out;

  prep_kernel<<<dim3(8192), 256, 0, stream>>>(
      Wq, Wk, Wv, Wo, Wt, query_in, key_in, value_in, Xb, mask, Mp);
  proj_qkv_kernel<<<dim3(768), 256, 0, stream>>>(Xb, Wt, bq, bk, bv, QKV);
  attn_kernel<<<dim3(512), 256, 0, stream>>>(Qb, Kb, VbT, Mp, Ctx);
  proj_out_kernel<<<dim3(256), 256, 0, stream>>>(Ctx, Wt + 3 * WSZ, bo, out);
}